// Round 5
// baseline (1087.417 us; speedup 1.0000x reference)
//
// TransformerDecoderBlock on MI355X (gfx950) — round 5: drain-free double-buffered attention.
// r4 found: time bound by per-tile serial chain (vmcnt(0) barrier drains + 8-way-conflict V reads),
// not HBM (FETCH fixed by XCD swizzle) and not occupancy-raisable (128 VGPR + 128 AGPR = 2 waves/SIMD).
// Fix: BK=16 with 2-deep K/V LDS buffers, staging issued one tile ahead, manual s_waitcnt vmcnt(8)
// + raw s_barrier (never drain to 0); PV via mfma 16x16x16 whose B-layout == S^T C-layout (the
// ds_bpermutes vanish); V^T read as ds_read_b64 (conflict-free banks). GEMM/LN unchanged.
#include <hip/hip_runtime.h>
#include <cstdint>
#include <cstddef>

#define NB 4
#define NS 4096
#define ND 512
#define NF 2048

typedef __bf16 bf16;
typedef __attribute__((ext_vector_type(8))) __bf16 bf16x8;
typedef __attribute__((ext_vector_type(4))) __bf16 bf16x4;
typedef __attribute__((ext_vector_type(4))) float f32x4;
typedef __attribute__((ext_vector_type(4))) short s16x4;

#define MFMA16(a, b, c) __builtin_amdgcn_mfma_f32_16x16x32_bf16((a), (b), (c), 0, 0, 0)
#if __has_builtin(__builtin_amdgcn_mfma_f32_16x16x16bf16_1k)
#define HAVE_MFMA16K16 1
#endif

// waitcnt imm (gfx9 encoding): vmcnt[3:0] | expcnt<<4 | lgkmcnt<<8 | vmcnt[5:4]<<14
#define WAIT_VM(n) __builtin_amdgcn_s_waitcnt(((n) & 0xF) | (7 << 4) | (0xF << 8) | (((n) >> 4) << 14))
#define CFENCE() asm volatile("" ::: "memory")

// Async global->LDS, 16B per lane. LDS dest is wave-uniform base; lane i lands at base+16*i.
__device__ __forceinline__ void async_copy16(void* lds, const void* g) {
  __builtin_amdgcn_global_load_lds(
      (__attribute__((address_space(1))) unsigned int*)(uintptr_t)g,
      (__attribute__((address_space(3))) unsigned int*)(unsigned)(uintptr_t)lds,
      16, 0, 0);
}

// ---------------- dtype detect ----------------
__global__ void k_detect(const unsigned short* __restrict__ x, unsigned* __restrict__ flag) {
  __shared__ int cnt;
  if (threadIdx.x == 0) cnt = 0;
  __syncthreads();
  int bad = 0;
  for (int i = threadIdx.x; i < 2048; i += 256) {
    unsigned e = (x[i] >> 7) & 0xFF;
    if (e < 100 || e > 140) bad++;
  }
  atomicAdd(&cnt, bad);
  __syncthreads();
  if (threadIdx.x == 0) *flag = (cnt > 200) ? 1u : 0u;  // 1 => inputs are f32
}

// ---------------- input normalization ----------------
__global__ void k_norm_bf16(const void* __restrict__ src, bf16* __restrict__ dst,
                            const unsigned* __restrict__ flag, int n) {
  int i = (blockIdx.x * 256 + threadIdx.x) * 8;
  if (i >= n) return;
  if (*flag) {
    const float* s = (const float*)src;
    float4 a = *(const float4*)(s + i);
    float4 c = *(const float4*)(s + i + 4);
    bf16x8 v;
    v[0] = (bf16)a.x; v[1] = (bf16)a.y; v[2] = (bf16)a.z; v[3] = (bf16)a.w;
    v[4] = (bf16)c.x; v[5] = (bf16)c.y; v[6] = (bf16)c.z; v[7] = (bf16)c.w;
    *(bf16x8*)(dst + i) = v;
  } else {
    *(uint4*)(dst + i) = *(const uint4*)((const bf16*)src + i);
  }
}

__global__ void k_norm_f32(const void* __restrict__ src, float* __restrict__ dst,
                           const unsigned* __restrict__ flag, int n) {
  int i = blockIdx.x * 256 + threadIdx.x;
  if (i >= n) return;
  dst[i] = (*flag) ? ((const float*)src)[i] : (float)((const bf16*)src)[i];
}

// ---------------- transpose [B][S][D] -> [B][D][S] (bf16) ----------------
__global__ void k_transpose(const bf16* __restrict__ in, bf16* __restrict__ out) {
  __shared__ bf16 t[64][72];
  const int b = blockIdx.z, s0 = blockIdx.x * 64, d0 = blockIdx.y * 64;
  const int tid = threadIdx.x;
#pragma unroll
  for (int it = 0; it < 2; ++it) {
    int slot = it * 256 + tid;
    int r = slot >> 3, c = (slot & 7) * 8;
    *(bf16x8*)&t[r][c] = *(const bf16x8*)&in[((size_t)b * NS + s0 + r) * ND + d0 + c];
  }
  __syncthreads();
#pragma unroll
  for (int it = 0; it < 2; ++it) {
    int slot = it * 256 + tid;
    int r = slot >> 3, c = (slot & 7) * 8;  // r = local dim, c = local seq base
    bf16x8 v;
#pragma unroll
    for (int k = 0; k < 8; ++k) v[k] = t[c + k][r];
    *(bf16x8*)&out[((size_t)b * ND + d0 + r) * NS + s0 + c] = v;
  }
}

// ---------------- flash attention: BK=16, double-buffered, drain-free barriers ----------------
// Grid: 512 1-D blocks. slot = blkid&7 -> (b = slot>>1, z = slot&1); q0 = (blkid>>3)*64 (XCD swizzle).
// Wave w owns q-rows [q0+w*16,+16). S^T = K*Q^T per 16-key tile (one 16x16 C-frag); its C-layout
// (k=quad*4+r, q=l15) equals the 16x16x16 B-operand layout, so P feeds PV in-lane (no shuffles).
template <bool CAUSAL>
__global__ __launch_bounds__(256, 2) void k_attn5(const bf16* __restrict__ Q,
                                                  const bf16* __restrict__ Km,
                                                  const bf16* __restrict__ Vt,
                                                  bf16* __restrict__ O0, bf16* __restrict__ O1,
                                                  float2* __restrict__ ml) {
  __shared__ bf16 lds_[32768];  // 64 KB: Ks[2][16][512] @0, Vs[2][512][16] @16384
  const int tid = threadIdx.x;
  const int w = tid >> 6, lane = tid & 63, quad = lane >> 4, l15 = lane & 15;
  const int slot = blockIdx.x & 7;
  const int b = slot >> 1;
  const int z = slot & 1;
  const int q0 = (int)(blockIdx.x >> 3) * 64;

  const bf16* Kg = Km + (size_t)b * NS * ND;
  const bf16* Vg = Vt + (size_t)b * ND * NS;

  // ---- Q fragments in registers, pre-scaled by 1/sqrt(D) ----
  const bf16* Qg = Q + ((size_t)b * NS + q0 + w * 16 + l15) * ND;
  bf16x8 qf[16];
#pragma unroll
  for (int s = 0; s < 16; ++s) qf[s] = *(const bf16x8*)&Qg[s * 32 + quad * 8];
#pragma unroll
  for (int s = 0; s < 16; ++s)
#pragma unroll
    for (int j = 0; j < 8; ++j) qf[s][j] = (bf16)((float)qf[s][j] * 0.044194173824159216f);

  f32x4 o[32];  // O^T: o[dt] -> (d = dt*16 + quad*4 + r, q = l15)
#pragma unroll
  for (int i = 0; i < 32; ++i) o[i] = (f32x4){0.f, 0.f, 0.f, 0.f};

  float m = -1e30f, l = 0.f;  // per-lane, q-row = l15 (replicated across quads)

  const int T = CAUSAL ? (q0 / 16 + 4) : (NS / 16);
  const int tA = (T + 1) >> 1;
  const int kt0 = z ? tA : 0;
  const int kt1 = z ? T : tA;

  // stage(tile, buf): 8 global_load_lds per wave (4 K-rows, 4 V-row-groups)
  auto stage = [&](int kt, int p) {
    const int k0 = kt * 16;
    bf16* KsP = lds_ + p * 8192;
    bf16* VsP = lds_ + 16384 + p * 8192;
#pragma unroll
    for (int i = 0; i < 4; ++i) {  // K rows w*4+i, XOR-swizzled 16B chunks
      const int r = w * 4 + i;
      const int g = (lane & ~7) | ((lane ^ r) & 7);
      async_copy16(&KsP[r * 512], Kg + (size_t)(k0 + r) * ND + g * 8);
    }
#pragma unroll
    for (int i = 0; i < 4; ++i) {  // V^T rows (dims): 32 per instr, 2 lanes/row
      const int dbase = (w * 4 + i) * 32;
      async_copy16(&VsP[dbase * 16], Vg + (size_t)(dbase + (lane >> 1)) * NS + k0 + (lane & 1) * 8);
    }
  };

  if (kt0 < kt1) stage(kt0, 0);

  for (int kt = kt0; kt < kt1; ++kt) {
    const int p = (kt - kt0) & 1;
    const bf16* KsP = lds_ + p * 8192;
    const bf16* VsP = lds_ + 16384 + p * 8192;
    const int k0 = kt * 16;

    if (kt + 1 < kt1) { stage(kt + 1, p ^ 1); CFENCE(); WAIT_VM(8); }
    else { CFENCE(); WAIT_VM(0); }
    __builtin_amdgcn_s_barrier();
    CFENCE();

    // ---- S^T = K * Q^T (one 16x16 tile) ----
    f32x4 sa = (f32x4){0.f, 0.f, 0.f, 0.f};
#pragma unroll
    for (int s = 0; s < 16; ++s) {
      const int lc = s * 4 + quad;
      const int swz = ((lc & ~7) | ((lc ^ l15) & 7)) * 8;
      bf16x8 a0 = *(const bf16x8*)&KsP[l15 * 512 + swz];
      sa = MFMA16(a0, qf[s], sa);
    }

    // ---- online softmax (wave-local; lane's q-row = l15, key = k0+quad*4+r) ----
    float sv[4];
    {
      const bool needMask = CAUSAL && (k0 + 15 > q0 + w * 16);
      const int qrow = q0 + w * 16 + l15;
#pragma unroll
      for (int r = 0; r < 4; ++r) {
        float s = sa[r];
        if (needMask && (k0 + quad * 4 + r > qrow)) s = -1e30f;
        sv[r] = s;
      }
    }
    float tm = fmaxf(fmaxf(sv[0], sv[1]), fmaxf(sv[2], sv[3]));
    tm = fmaxf(tm, __shfl_xor(tm, 16));
    tm = fmaxf(tm, __shfl_xor(tm, 32));
    const float mn = fmaxf(m, tm);
    const float alpha = __expf(m - mn);
    m = mn;
    float pf[4];
#pragma unroll
    for (int r = 0; r < 4; ++r) pf[r] = __expf(sv[r] - mn);
    float ts = pf[0] + pf[1] + pf[2] + pf[3];
    ts += __shfl_xor(ts, 16);
    ts += __shfl_xor(ts, 32);
    l = l * alpha + ts;
    if (__ballot(alpha < 0.99999f)) {
#pragma unroll
      for (int dt = 0; dt < 32; ++dt)
#pragma unroll
        for (int r = 0; r < 4; ++r) o[dt][r] *= alpha;
    }

    // ---- PV: O^T += V^T * P. P's C-layout == 16x16x16 B-layout: in-lane. ----
#if HAVE_MFMA16K16
    bf16x4 pb4;
#pragma unroll
    for (int r = 0; r < 4; ++r) pb4[r] = (bf16)pf[r];
    const s16x4 vb = __builtin_bit_cast(s16x4, pb4);
#pragma unroll
    for (int dt = 0; dt < 32; ++dt) {
      const s16x4 va = *(const s16x4*)&VsP[(dt * 16 + l15) * 16 + quad * 4];
      o[dt] = __builtin_amdgcn_mfma_f32_16x16x16bf16_1k(va, vb, o[dt], 0, 0, 0);
    }
#else
    // fallback: zero-padded 16x16x32; B needs cross-quad P via bpermute (k=quad*8+j, j<8)
    bf16x8 pb;
#pragma unroll
    for (int j = 0; j < 8; ++j) {
      const int k = quad * 8 + j;
      if (k < 16) {
        const int sl = ((k >> 2) * 16 + l15) * 4;
        float v = __int_as_float(__builtin_amdgcn_ds_bpermute(sl, __float_as_int(pf[k & 3])));
        pb[j] = (bf16)v;
      } else {
        pb[j] = (bf16)0.f;
      }
    }
#pragma unroll
    for (int dt = 0; dt < 32; ++dt) {
      bf16x8 a;
      const bf16* row = &VsP[(dt * 16 + l15) * 16];
#pragma unroll
      for (int j = 0; j < 8; ++j) {
        const int k = quad * 8 + j;
        a[j] = (k < 16) ? row[k] : (bf16)0.f;
      }
      o[dt] = MFMA16(a, pb, o[dt]);
    }
#endif

    CFENCE();
    __builtin_amdgcn_s_barrier();  // ds_reads of buf p already consumed; protects p from kt+2 staging
    CFENCE();
  }

  // ---- epilogue: normalize by 1/l, write partial + (m,l); LDS transpose for coalesced O ----
  __syncthreads();
  const float inv = 1.f / l;
  if (lane < 16 && quad == 0) ml[((size_t)z * NB + b) * NS + q0 + w * 16 + lane] = make_float2(m, l);
  bf16* Ow = lds_ + w * 8192;  // 16 KB per wave: [16 q][512 d]
#pragma unroll
  for (int dt = 0; dt < 32; ++dt) {
    bf16x4 v;
#pragma unroll
    for (int r = 0; r < 4; ++r) v[r] = (bf16)(o[dt][r] * inv);
    *(bf16x4*)&Ow[l15 * 512 + dt * 16 + quad * 4] = v;
  }
  __syncthreads();
  bf16* Og = (z ? O1 : O0) + ((size_t)b * NS + q0 + w * 16) * ND;
#pragma unroll
  for (int it = 0; it < 16; ++it) {
    bf16x8 row = *(const bf16x8*)&Ow[it * 512 + lane * 8];
    *(bf16x8*)&Og[(size_t)it * ND + lane * 8] = row;
  }
}

// ---------------- merge two K-split partials: O0 = c0*O0 + c1*O1 ----------------
__global__ void k_merge(bf16* __restrict__ O0, const bf16* __restrict__ O1,
                        const float2* __restrict__ ml) {
  size_t i = ((size_t)blockIdx.x * 256 + threadIdx.x) * 8;
  int row = (int)(i >> 9);  // / 512
  float2 a = ml[row];
  float2 c = ml[(size_t)NB * NS + row];
  float M = fmaxf(a.x, c.x);
  float w0 = __expf(a.x - M) * a.y;
  float w1 = __expf(c.x - M) * c.y;
  float den = 1.f / (w0 + w1);
  float c0 = w0 * den, c1 = w1 * den;
  bf16x8 v0 = *(const bf16x8*)(O0 + i);
  bf16x8 v1 = *(const bf16x8*)(O1 + i);
  bf16x8 ov;
#pragma unroll
  for (int k = 0; k < 8; ++k) ov[k] = (bf16)(c0 * (float)v0[k] + c1 * (float)v1[k]);
  *(bf16x8*)(O0 + i) = ov;
}

// ---------------- NT GEMM: Out[M,N] = A[M,K] * W[N,K]^T (+bias)(+relu)(+res)(+LN stats) ----------------
template <int RES_MODE, bool HAS_BIAS, bool RELU, bool STATS>
__global__ __launch_bounds__(256) void k_gemm(const bf16* __restrict__ A, const bf16* __restrict__ W,
                                              const bf16* __restrict__ resid,
                                              const float* __restrict__ bias, bf16* __restrict__ Out,
                                              float* __restrict__ stats, int M, int N, int K,
                                              int rowOfs) {
  __shared__ bf16 As[128 * 64];
  __shared__ bf16 Ws[128 * 64];
  const int tid = threadIdx.x;
  const int w = tid >> 6, lane = tid & 63, quad = lane >> 4, l15 = lane & 15;
  const int m0 = blockIdx.x * 128, n0 = blockIdx.y * 128;
  const int wr = (w >> 1) * 64, wc = (w & 1) * 64;
  const int arow = lane >> 3, acol = (lane & 7) * 8;

  f32x4 acc[16];
#pragma unroll
  for (int i = 0; i < 16; ++i) acc[i] = (f32x4){0.f, 0.f, 0.f, 0.f};

  for (int k0 = 0; k0 < K; k0 += 64) {
    __syncthreads();
#pragma unroll
    for (int i = 0; i < 4; ++i) {
      const int rbase = (w * 4 + i) * 8 + arow;
      async_copy16(&As[(w * 4 + i) * 512], A + (size_t)(m0 + rbase) * K + k0 + acol);
      async_copy16(&Ws[(w * 4 + i) * 512], W + (size_t)(n0 + rbase) * K + k0 + acol);
    }
    __syncthreads();
#pragma unroll
    for (int s = 0; s < 2; ++s) {
      bf16x8 af[4], bw[4];
#pragma unroll
      for (int i = 0; i < 4; ++i) af[i] = *(const bf16x8*)&As[(wr + i * 16 + l15) * 64 + s * 32 + quad * 8];
#pragma unroll
      for (int j = 0; j < 4; ++j) bw[j] = *(const bf16x8*)&Ws[(wc + j * 16 + l15) * 64 + s * 32 + quad * 8];
#pragma unroll
      for (int i = 0; i < 4; ++i)
#pragma unroll
        for (int j = 0; j < 4; ++j) acc[i * 4 + j] = MFMA16(af[i], bw[j], acc[i * 4 + j]);
    }
  }

  float lsum = 0.f, lsq = 0.f;
#pragma unroll
  for (int i = 0; i < 4; ++i)
#pragma unroll
    for (int j = 0; j < 4; ++j)
#pragma unroll
      for (int r = 0; r < 4; ++r) {
        int row = m0 + wr + i * 16 + quad * 4 + r;
        int col = n0 + wc + j * 16 + l15;
        float v = acc[i * 4 + j][r];
        if (HAS_BIAS) v += bias[col];
        if (RELU) v = fmaxf(v, 0.f);
        if (RES_MODE == 2) v += (float)resid[(size_t)row * N + col];
        Out[(size_t)row * N + col] = (bf16)v;
        if (STATS) { lsum += v; lsq += v * v; }
      }

  if (STATS) {
    __syncthreads();
    float* red = (float*)As;
    red[tid] = lsum;
    red[256 + tid] = lsq;
    __syncthreads();
    for (int off = 128; off > 0; off >>= 1) {
      if (tid < off) { red[tid] += red[tid + off]; red[256 + tid] += red[256 + tid + off]; }
      __syncthreads();
    }
    if (tid == 0) {
      int bidx = (rowOfs + m0) >> 12;  // 4096 rows per batch
      atomicAdd(&stats[bidx * 2], red[0]);
      atomicAdd(&stats[bidx * 2 + 1], red[256]);
    }
  }
}

// ---------------- LayerNorm apply over (S,D) jointly per batch ----------------
template <bool FINAL>
__global__ void k_ln(const bf16* __restrict__ T, const float* __restrict__ stats,
                     const void* __restrict__ gp, const void* __restrict__ bp,
                     void* __restrict__ outp, const unsigned* __restrict__ flag) {
  const float invN = 1.f / 2097152.f;
  size_t i = ((size_t)(blockIdx.x * 256 + threadIdx.x)) * 8;
  int b = (int)(i >> 21);
  int sd = (int)(i & 2097151);
  float mu = stats[b * 2] * invN;
  float var = stats[b * 2 + 1] * invN - mu * mu;
  float rs = rsqrtf(var + 1e-5f);
  bool f32m = (*flag != 0);
  bf16x8 tv = *(const bf16x8*)(T + i);
  float gv[8], bv[8];
  if (f32m) {
    float4 a = *(const float4*)((const float*)gp + sd), c = *(const float4*)((const float*)gp + sd + 4);
    gv[0] = a.x; gv[1] = a.y; gv[2] = a.z; gv[3] = a.w; gv[4] = c.x; gv[5] = c.y; gv[6] = c.z; gv[7] = c.w;
    float4 e = *(const float4*)((const float*)bp + sd), f = *(const float4*)((const float*)bp + sd + 4);
    bv[0] = e.x; bv[1] = e.y; bv[2] = e.z; bv[3] = e.w; bv[4] = f.x; bv[5] = f.y; bv[6] = f.z; bv[7] = f.w;
  } else {
    bf16x8 g8 = *(const bf16x8*)((const bf16*)gp + sd);
    bf16x8 b8 = *(const bf16x8*)((const bf16*)bp + sd);
#pragma unroll
    for (int k = 0; k < 8; ++k) { gv[k] = (float)g8[k]; bv[k] = (float)b8[k]; }
  }
  float ov[8];
#pragma unroll
  for (int k = 0; k < 8; ++k) ov[k] = ((float)tv[k] - mu) * rs * gv[k] + bv[k];
  if (FINAL && f32m) {
    float4 o0 = {ov[0], ov[1], ov[2], ov[3]}, o1 = {ov[4], ov[5], ov[6], ov[7]};
    *(float4*)((float*)outp + i) = o0;
    *(float4*)((float*)outp + i + 4) = o1;
  } else {
    bf16x8 o8;
#pragma unroll
    for (int k = 0; k < 8; ++k) o8[k] = (bf16)ov[k];
    *(bf16x8*)((bf16*)outp + i) = o8;
  }
}

// ---------------- fused LayerNorm + transpose: X = LN(T), XT = X^T ----------------
__global__ void k_ln_t(const bf16* __restrict__ T, const float* __restrict__ stats,
                       const void* __restrict__ gp, const void* __restrict__ bp,
                       bf16* __restrict__ X, bf16* __restrict__ XT,
                       const unsigned* __restrict__ flag) {
  __shared__ bf16 t[64][72];
  const float invN = 1.f / 2097152.f;
  const int b = blockIdx.z, s0 = blockIdx.x * 64, d0 = blockIdx.y * 64;
  const int tid = threadIdx.x;
  const float mu = stats[b * 2] * invN;
  const float var = stats[b * 2 + 1] * invN - mu * mu;
  const float rs = rsqrtf(var + 1e-5f);
  const bool f32m = (*flag != 0);
#pragma unroll
  for (int it = 0; it < 2; ++it) {
    int slot = it * 256 + tid;
    int r = slot >> 3, c = (slot & 7) * 8;
    size_t idx = ((size_t)b * NS + s0 + r) * ND + d0 + c;
    size_t pidx = (size_t)(s0 + r) * ND + d0 + c;
    bf16x8 tv = *(const bf16x8*)&T[idx];
    float gv[8], bv[8];
    if (f32m) {
      float4 a = *(const float4*)((const float*)gp + pidx), cc = *(const float4*)((const float*)gp + pidx + 4);
      gv[0] = a.x; gv[1] = a.y; gv[2] = a.z; gv[3] = a.w; gv[4] = cc.x; gv[5] = cc.y; gv[6] = cc.z; gv[7] = cc.w;
      float4 e = *(const float4*)((const float*)bp + pidx), f = *(const float4*)((const float*)bp + pidx + 4);
      bv[0] = e.x; bv[1] = e.y; bv[2] = e.z; bv[3] = e.w; bv[4] = f.x; bv[5] = f.y; bv[6] = f.z; bv[7] = f.w;
    } else {
      bf16x8 g8 = *(const bf16x8*)((const bf16*)gp + pidx);
      bf16x8 b8 = *(const bf16x8*)((const bf16*)bp + pidx);
#pragma unroll
      for (int k = 0; k < 8; ++k) { gv[k] = (float)g8[k]; bv[k] = (float)b8[k]; }
    }
    bf16x8 ov;
#pragma unroll
    for (int k = 0; k < 8; ++k) ov[k] = (bf16)(((float)tv[k] - mu) * rs * gv[k] + bv[k]);
    *(bf16x8*)&X[idx] = ov;
    *(bf16x8*)&t[r][c] = ov;
  }
  __syncthreads();
#pragma unroll
  for (int it = 0; it < 2; ++it) {
    int slot = it * 256 + tid;
    int r = slot >> 3, c = (slot & 7) * 8;  // r = local dim, c = local seq base
    bf16x8 v;
#pragma unroll
    for (int k = 0; k < 8; ++k) v[k] = t[c + k][r];
    *(bf16x8*)&XT[((size_t)b * ND + d0 + r) * NS + s0 + c] = v;
  }
}

// ---------------- launch ----------------
extern "C" void kernel_launch(void* const* d_in, const int* in_sizes, int n_in, void* d_out,
                              int out_size, void* d_ws, size_t ws_size, hipStream_t stream) {
  (void)in_sizes; (void)n_in; (void)out_size;
  const void* x_raw = d_in[0];
  const void* enc_raw = d_in[1];
  const void* Wo1_raw = d_in[2];
  const void* Wo2_raw = d_in[3];
  const void* g1_raw = d_in[4];
  const void* bb1_raw = d_in[5];
  const void* g2_raw = d_in[6];
  const void* bb2_raw = d_in[7];
  const void* W1_raw = d_in[8];
  const void* bias1_raw = d_in[9];
  const void* W2_raw = d_in[10];
  const void* bias2_raw = d_in[11];

  char* w = (char*)d_ws;
  unsigned* flag = (unsigned*)(w + 0);
  float* stats = (float*)(w + 16);  // 3 stages x [B][2]
  float* b1f = (float*)(w + 1024);
  float* b2f = (float*)(w + 1024 + 8192);
  size_t off = 16384;
  const size_t nBSD = (size_t)NB * NS * ND;
  bf16* Wo1b = (bf16*)(w + off); off += (size_t)ND * ND * 2;
  bf16* Wo2b = (bf16*)(w + off); off += (size_t)ND * ND * 2;
  bf16* W1b = (bf16*)(w + off); off += (size_t)NF * ND * 2;
  bf16* W2b = (bf16*)(w + off); off += (size_t)ND * NF * 2;
  bf16* xb = (bf16*)(w + off); off += nBSD * 2;   // x bf16, later enc
  bf16* Ab = (bf16*)(w + off); off += nBSD * 2;
  bf16* Tb = (bf16*)(w + off); off += nBSD * 2;
  bf16* X1b = (bf16*)(w + off); off += nBSD * 2;
  bf16* Hb = (bf16*)(w + off); off += (size_t)8192 * NF * 2;  // FFN hidden; attn partial-1 + ml earlier
  if (ws_size < off) return;

  bf16* O1b = Hb;                                 // partial-1 region (Hb dead until FFN)
  float2* mlb = (float2*)((char*)Hb + nBSD * 2);  // 2*B*S float2 = 256 KB

  hipMemsetAsync(stats, 0, 24 * sizeof(float), stream);
  k_detect<<<1, 256, 0, stream>>>((const unsigned short*)x_raw, flag);

  k_norm_bf16<<<(int)(nBSD / 2048), 256, 0, stream>>>(x_raw, xb, flag, (int)nBSD);
  k_norm_bf16<<<(ND * ND) / 2048, 256, 0, stream>>>(Wo1_raw, Wo1b, flag, ND * ND);
  k_norm_bf16<<<(ND * ND) / 2048, 256, 0, stream>>>(Wo2_raw, Wo2b, flag, ND * ND);
  k_norm_bf16<<<(NF * ND) / 2048, 256, 0, stream>>>(W1_raw, W1b, flag, NF * ND);
  k_norm_bf16<<<(NF * ND) / 2048, 256, 0, stream>>>(W2_raw, W2b, flag, ND * NF);
  k_norm_f32<<<8, 256, 0, stream>>>(bias1_raw, b1f, flag, NF);
  k_norm_f32<<<2, 256, 0, stream>>>(bias2_raw, b2f, flag, ND);

  // 1) causal self-attention + Wo1 + residual(x) + LN1 (fused with transpose for cross-attn V)
  k_transpose<<<dim3(NS / 64, ND / 64, NB), 256, 0, stream>>>(xb, Tb);  // x^T as V
  k_attn5<true><<<512, 256, 0, stream>>>(xb, xb, Tb, Ab, O1b, mlb);
  k_merge<<<(int)(nBSD / 2048), 256, 0, stream>>>(Ab, O1b, mlb);
  k_gemm<2, false, false, true><<<dim3(128, 4), 256, 0, stream>>>(Ab, Wo1b, xb, nullptr, Tb,
                                                                  stats + 0, NB * NS, ND, ND, 0);
  k_ln_t<<<dim3(NS / 64, ND / 64, NB), 256, 0, stream>>>(Tb, stats + 0, g1_raw, bb1_raw, X1b, Ab,
                                                         flag);  // X1 -> X1b, X1^T -> Ab
  k_norm_bf16<<<(int)(nBSD / 2048), 256, 0, stream>>>(enc_raw, xb, flag, (int)nBSD);  // xb := enc

  // 2) cross attention (q=k=enc, v=X1) + Wo2 + residual(X1) + LN2
  k_attn5<false><<<512, 256, 0, stream>>>(xb, xb, Ab, Tb, O1b, mlb);  // O0 -> Tb
  k_merge<<<(int)(nBSD / 2048), 256, 0, stream>>>(Tb, O1b, mlb);
  k_gemm<2, false, false, true><<<dim3(128, 4), 256, 0, stream>>>(Tb, Wo2b, X1b, nullptr, Ab,
                                                                  stats + 8, NB * NS, ND, ND, 0);
  k_ln<false><<<(int)(nBSD / 2048), 256, 0, stream>>>(Ab, stats + 8, g2_raw, bb2_raw, X1b, flag);
  // X1b now holds X2

  // 3) FFN + residual(X2) + LN (ln2 params), in two 8192-row chunks
  for (int c = 0; c < 2; ++c) {
    size_t ro = (size_t)c * 8192;
    k_gemm<0, true, true, false><<<dim3(64, 16), 256, 0, stream>>>(X1b + ro * ND, W1b, nullptr, b1f,
                                                                   Hb, nullptr, 8192, NF, ND, 0);
    k_gemm<2, true, false, true><<<dim3(64, 4), 256, 0, stream>>>(Hb, W2b, X1b + ro * ND, b2f,
                                                                  Tb + ro * ND, stats + 16, 8192,
                                                                  ND, NF, (int)ro);
  }
  k_ln<true><<<(int)(nBSD / 2048), 256, 0, stream>>>(Tb, stats + 16, g2_raw, bb2_raw, d_out, flag);
}

// Round 6
// 947.041 us; speedup vs baseline: 1.1482x; 1.1482x over previous
//
// TransformerDecoderBlock on MI355X (gfx950) — round 6: r4 attention core + swizzled-V global
// layout (kills the PV b128 8-way bank conflict for free; swizzle applied where V^T is produced,
// staging is 16B-chunk-linear so LDS inherits it) + full-M FFN when workspace allows (FFN2 grid
// 256->512 blocks = 2/CU). Attention: BQ=64, BK=32, Q-in-regs, S^T=K*Q^T wave-local softmax,
// ds_bpermute P^T, O^T acc, 2-way K-split, XCD swizzle (b,z)=blkid&7. r5's BK=16 reverted (regressed).
#include <hip/hip_runtime.h>
#include <cstdint>
#include <cstddef>

#define NB 4
#define NS 4096
#define ND 512
#define NF 2048

typedef __bf16 bf16;
typedef __attribute__((ext_vector_type(8))) __bf16 bf16x8;
typedef __attribute__((ext_vector_type(4))) __bf16 bf16x4;
typedef __attribute__((ext_vector_type(4))) float f32x4;

#define MFMA16(a, b, c) __builtin_amdgcn_mfma_f32_16x16x32_bf16((a), (b), (c), 0, 0, 0)

// Async global->LDS, 16B per lane. LDS dest is wave-uniform base; lane i lands at base+16*i.
__device__ __forceinline__ void async_copy16(void* lds, const void* g) {
  __builtin_amdgcn_global_load_lds(
      (__attribute__((address_space(1))) unsigned int*)(uintptr_t)g,
      (__attribute__((address_space(3))) unsigned int*)(unsigned)(uintptr_t)lds,
      16, 0, 0);
}

// V^T global k-swizzle: within each 32-k block, 8-elem chunk c of dim-row d is stored at
// chunk ((c + (d>>1)) & 3). Makes the attention PV ds_read_b128 conflict-free.
__device__ __forceinline__ int vswz_col(int c /*mult of 8 in [0,64)*/, int dloc) {
  return (c & ~31) | (((((c >> 3) & 3) + ((dloc >> 1) & 3)) & 3) << 3);
}

// ---------------- dtype detect ----------------
__global__ void k_detect(const unsigned short* __restrict__ x, unsigned* __restrict__ flag) {
  __shared__ int cnt;
  if (threadIdx.x == 0) cnt = 0;
  __syncthreads();
  int bad = 0;
  for (int i = threadIdx.x; i < 2048; i += 256) {
    unsigned e = (x[i] >> 7) & 0xFF;
    if (e < 100 || e > 140) bad++;
  }
  atomicAdd(&cnt, bad);
  __syncthreads();
  if (threadIdx.x == 0) *flag = (cnt > 200) ? 1u : 0u;  // 1 => inputs are f32
}

// ---------------- input normalization ----------------
__global__ void k_norm_bf16(const void* __restrict__ src, bf16* __restrict__ dst,
                            const unsigned* __restrict__ flag, int n) {
  int i = (blockIdx.x * 256 + threadIdx.x) * 8;
  if (i >= n) return;
  if (*flag) {
    const float* s = (const float*)src;
    float4 a = *(const float4*)(s + i);
    float4 c = *(const float4*)(s + i + 4);
    bf16x8 v;
    v[0] = (bf16)a.x; v[1] = (bf16)a.y; v[2] = (bf16)a.z; v[3] = (bf16)a.w;
    v[4] = (bf16)c.x; v[5] = (bf16)c.y; v[6] = (bf16)c.z; v[7] = (bf16)c.w;
    *(bf16x8*)(dst + i) = v;
  } else {
    *(uint4*)(dst + i) = *(const uint4*)((const bf16*)src + i);
  }
}

__global__ void k_norm_f32(const void* __restrict__ src, float* __restrict__ dst,
                           const unsigned* __restrict__ flag, int n) {
  int i = blockIdx.x * 256 + threadIdx.x;
  if (i >= n) return;
  dst[i] = (*flag) ? ((const float*)src)[i] : (float)((const bf16*)src)[i];
}

// ---------------- transpose [B][S][D] -> [B][D][S] (bf16), k-swizzled output ----------------
__global__ void k_transpose(const bf16* __restrict__ in, bf16* __restrict__ out) {
  __shared__ bf16 t[64][72];
  const int b = blockIdx.z, s0 = blockIdx.x * 64, d0 = blockIdx.y * 64;
  const int tid = threadIdx.x;
#pragma unroll
  for (int it = 0; it < 2; ++it) {
    int slot = it * 256 + tid;
    int r = slot >> 3, c = (slot & 7) * 8;
    *(bf16x8*)&t[r][c] = *(const bf16x8*)&in[((size_t)b * NS + s0 + r) * ND + d0 + c];
  }
  __syncthreads();
#pragma unroll
  for (int it = 0; it < 2; ++it) {
    int slot = it * 256 + tid;
    int r = slot >> 3, c = (slot & 7) * 8;  // r = local dim, c = local seq base
    bf16x8 v;
#pragma unroll
    for (int k = 0; k < 8; ++k) v[k] = t[c + k][r];
    *(bf16x8*)&out[((size_t)b * ND + d0 + r) * NS + s0 + vswz_col(c, r)] = v;
  }
}

// ---------------- flash attention (r4 core + conflict-free swizzled V reads) ----------------
// Grid: 512 blocks. slot = blkid&7 -> (b = slot>>1, z = slot&1); q0 = (blkid>>3)*64 (XCD locality).
template <bool CAUSAL>
__global__ __launch_bounds__(256, 2) void k_attn6(const bf16* __restrict__ Q,
                                                  const bf16* __restrict__ Km,
                                                  const bf16* __restrict__ Vt,
                                                  bf16* __restrict__ O0, bf16* __restrict__ O1,
                                                  float2* __restrict__ ml) {
  __shared__ bf16 lds_[32768];  // 64 KB: Ks [32 x 512], Vs [512 x 32] (k-swizzled)
  bf16* Ks = lds_;
  bf16* Vs = lds_ + 16384;

  const int tid = threadIdx.x;
  const int w = tid >> 6, lane = tid & 63, quad = lane >> 4, l15 = lane & 15;
  const int slot = blockIdx.x & 7;
  const int b = slot >> 1;
  const int z = slot & 1;
  const int q0 = (int)(blockIdx.x >> 3) * 64;

  const bf16* Kg = Km + (size_t)b * NS * ND;
  const bf16* Vg = Vt + (size_t)b * ND * NS;

  // ---- Q fragments in registers, pre-scaled by 1/sqrt(D) ----
  const bf16* Qg = Q + ((size_t)b * NS + q0 + w * 16 + l15) * ND;
  bf16x8 qf[16];
#pragma unroll
  for (int s = 0; s < 16; ++s) qf[s] = *(const bf16x8*)&Qg[s * 32 + quad * 8];
#pragma unroll
  for (int s = 0; s < 16; ++s)
#pragma unroll
    for (int j = 0; j < 8; ++j) qf[s][j] = (bf16)((float)qf[s][j] * 0.044194173824159216f);

  f32x4 o[32];  // O^T: o[dt] -> (d = dt*16 + quad*4 + r, q = l15)
#pragma unroll
  for (int i = 0; i < 32; ++i) o[i] = (f32x4){0.f, 0.f, 0.f, 0.f};

  float m = -1e30f, l = 0.f;  // per-lane, q = l15 (replicated across quads)

  const int T = CAUSAL ? (q0 / 32 + 2) : (NS / 32);
  const int tA = (T + 1) >> 1;
  const int kt0 = z ? tA : 0;
  const int kt1 = z ? T : tA;
  const int laneA4 = ((((quad * 2) & 3) * 16) + l15) * 4;
  const int laneB4 = ((((quad * 2 + 1) & 3) * 16) + l15) * 4;
  const int vsw = ((quad + ((l15 >> 1) & 3)) & 3) * 8;  // swizzled V chunk offset (elements)

  for (int kt = kt0; kt < kt1; ++kt) {
    const int k0 = kt * 32;
    __syncthreads();  // previous tile's LDS reads complete

    // ---- stage K tile [32][512] with per-row XOR-swizzle on 16B chunks ----
#pragma unroll
    for (int i = 0; i < 8; ++i) {
      const int r = w * 8 + i;
      const int g = (lane & ~7) | ((lane ^ r) & 7);
      async_copy16(&Ks[r * 512], Kg + (size_t)(k0 + r) * ND + g * 8);
    }
    // ---- stage V^T tile [512][32] (global already k-swizzled; copy is chunk-linear) ----
#pragma unroll
    for (int i = 0; i < 8; ++i) {
      const int d0 = (w * 8 + i) * 16;
      async_copy16(&Vs[d0 * 32], Vg + (size_t)(d0 + (lane >> 2)) * NS + k0 + (lane & 3) * 8);
    }
    __syncthreads();  // staging drained

    // ---- S^T = K * Q^T ----
    f32x4 sa0 = (f32x4){0.f, 0.f, 0.f, 0.f};
    f32x4 sa1 = (f32x4){0.f, 0.f, 0.f, 0.f};
#pragma unroll
    for (int s = 0; s < 16; ++s) {
      const int lc = s * 4 + quad;
      const int swz = ((lc & ~7) | ((lc ^ l15) & 7)) * 8;
      bf16x8 a0 = *(const bf16x8*)&Ks[l15 * 512 + swz];
      bf16x8 a1 = *(const bf16x8*)&Ks[(16 + l15) * 512 + swz];
      sa0 = MFMA16(a0, qf[s], sa0);
      sa1 = MFMA16(a1, qf[s], sa1);
    }

    // ---- online softmax (fully wave-local; lane's q-row = l15) ----
    float sv[8];
    {
      const int qrow = q0 + w * 16 + l15;
      const bool needMask = CAUSAL && (k0 + 31 > q0 + w * 16);
#pragma unroll
      for (int kt2 = 0; kt2 < 2; ++kt2)
#pragma unroll
        for (int r = 0; r < 4; ++r) {
          float s = (kt2 == 0) ? sa0[r] : sa1[r];
          if (needMask) {
            int key = k0 + kt2 * 16 + quad * 4 + r;
            if (key > qrow) s = -1e30f;
          }
          sv[kt2 * 4 + r] = s;
        }
    }
    float tm = sv[0];
#pragma unroll
    for (int i = 1; i < 8; ++i) tm = fmaxf(tm, sv[i]);
    tm = fmaxf(tm, __shfl_xor(tm, 16));
    tm = fmaxf(tm, __shfl_xor(tm, 32));
    const float mn = fmaxf(m, tm);
    const float alpha = __expf(m - mn);
    m = mn;
    float pf[8];
    float ts = 0.f;
#pragma unroll
    for (int i = 0; i < 8; ++i) { pf[i] = __expf(sv[i] - mn); ts += pf[i]; }
    ts += __shfl_xor(ts, 16);
    ts += __shfl_xor(ts, 32);
    l = l * alpha + ts;
    if (__ballot(alpha < 0.99999f)) {
#pragma unroll
      for (int dt = 0; dt < 32; ++dt)
#pragma unroll
        for (int r = 0; r < 4; ++r) o[dt][r] *= alpha;
    }

    // ---- P^T (C-layout) -> B-operand frag via ds_bpermute, no LDS ----
    bf16x8 pb;
#pragma unroll
    for (int j = 0; j < 8; ++j) {
      const int r_ = j & 3;
      const int sl = (j < 4) ? laneA4 : laneB4;
      float v0 = __int_as_float(__builtin_amdgcn_ds_bpermute(sl, __float_as_int(pf[r_])));
      float v1 = __int_as_float(__builtin_amdgcn_ds_bpermute(sl, __float_as_int(pf[4 + r_])));
      pb[j] = (bf16)(quad < 2 ? v0 : v1);
    }

    // ---- O^T += V^T * P (swizzled V read: conflict-free b128) ----
#pragma unroll
    for (int dt = 0; dt < 32; ++dt) {
      // logical element (d = dt*16+l15, k = quad*8..+8) at swizzled chunk vsw
      bf16x8 a = *(const bf16x8*)&Vs[(dt * 16 + l15) * 32 + vsw];
      o[dt] = MFMA16(a, pb, o[dt]);
    }
  }

  // ---- epilogue: normalize by 1/l, write partial + (m,l) ----
  __syncthreads();
  const float inv = 1.f / l;
  if (lane < 16 && quad == 0) ml[((size_t)z * NB + b) * NS + q0 + w * 16 + lane] = make_float2(m, l);
  bf16* Ow = lds_ + w * 8192;  // 16 KB per wave: [16 q][512 d]
#pragma unroll
  for (int dt = 0; dt < 32; ++dt) {
    bf16x4 v;
#pragma unroll
    for (int r = 0; r < 4; ++r) v[r] = (bf16)(o[dt][r] * inv);
    *(bf16x4*)&Ow[l15 * 512 + dt * 16 + quad * 4] = v;
  }
  bf16* Og = (z ? O1 : O0) + ((size_t)b * NS + q0 + w * 16) * ND;
#pragma unroll
  for (int it = 0; it < 16; ++it) {
    bf16x8 row = *(const bf16x8*)&Ow[it * 512 + lane * 8];
    *(bf16x8*)&Og[(size_t)it * ND + lane * 8] = row;
  }
}

// ---------------- merge two K-split partials: O0 = c0*O0 + c1*O1 ----------------
__global__ void k_merge(bf16* __restrict__ O0, const bf16* __restrict__ O1,
                        const float2* __restrict__ ml) {
  size_t i = ((size_t)blockIdx.x * 256 + threadIdx.x) * 8;
  int row = (int)(i >> 9);  // / 512
  float2 a = ml[row];
  float2 c = ml[(size_t)NB * NS + row];
  float M = fmaxf(a.x, c.x);
  float w0 = __expf(a.x - M) * a.y;
  float w1 = __expf(c.x - M) * c.y;
  float den = 1.f / (w0 + w1);
  float c0 = w0 * den, c1 = w1 * den;
  bf16x8 v0 = *(const bf16x8*)(O0 + i);
  bf16x8 v1 = *(const bf16x8*)(O1 + i);
  bf16x8 ov;
#pragma unroll
  for (int k = 0; k < 8; ++k) ov[k] = (bf16)(c0 * (float)v0[k] + c1 * (float)v1[k]);
  *(bf16x8*)(O0 + i) = ov;
}

// ---------------- NT GEMM: Out[M,N] = A[M,K] * W[N,K]^T (+bias)(+relu)(+res)(+LN stats) ----------------
template <int RES_MODE, bool HAS_BIAS, bool RELU, bool STATS>
__global__ __launch_bounds__(256) void k_gemm(const bf16* __restrict__ A, const bf16* __restrict__ W,
                                              const bf16* __restrict__ resid,
                                              const float* __restrict__ bias, bf16* __restrict__ Out,
                                              float* __restrict__ stats, int M, int N, int K,
                                              int rowOfs) {
  __shared__ bf16 As[128 * 64];
  __shared__ bf16 Ws[128 * 64];
  const int tid = threadIdx.x;
  const int w = tid >> 6, lane = tid & 63, quad = lane >> 4, l15 = lane & 15;
  const int m0 = blockIdx.x * 128, n0 = blockIdx.y * 128;
  const int wr = (w >> 1) * 64, wc = (w & 1) * 64;
  const int arow = lane >> 3, acol = (lane & 7) * 8;

  f32x4 acc[16];
#pragma unroll
  for (int i = 0; i < 16; ++i) acc[i] = (f32x4){0.f, 0.f, 0.f, 0.f};

  for (int k0 = 0; k0 < K; k0 += 64) {
    __syncthreads();
#pragma unroll
    for (int i = 0; i < 4; ++i) {
      const int rbase = (w * 4 + i) * 8 + arow;
      async_copy16(&As[(w * 4 + i) * 512], A + (size_t)(m0 + rbase) * K + k0 + acol);
      async_copy16(&Ws[(w * 4 + i) * 512], W + (size_t)(n0 + rbase) * K + k0 + acol);
    }
    __syncthreads();
#pragma unroll
    for (int s = 0; s < 2; ++s) {
      bf16x8 af[4], bw[4];
#pragma unroll
      for (int i = 0; i < 4; ++i) af[i] = *(const bf16x8*)&As[(wr + i * 16 + l15) * 64 + s * 32 + quad * 8];
#pragma unroll
      for (int j = 0; j < 4; ++j) bw[j] = *(const bf16x8*)&Ws[(wc + j * 16 + l15) * 64 + s * 32 + quad * 8];
#pragma unroll
      for (int i = 0; i < 4; ++i)
#pragma unroll
        for (int j = 0; j < 4; ++j) acc[i * 4 + j] = MFMA16(af[i], bw[j], acc[i * 4 + j]);
    }
  }

  float lsum = 0.f, lsq = 0.f;
#pragma unroll
  for (int i = 0; i < 4; ++i)
#pragma unroll
    for (int j = 0; j < 4; ++j)
#pragma unroll
      for (int r = 0; r < 4; ++r) {
        int row = m0 + wr + i * 16 + quad * 4 + r;
        int col = n0 + wc + j * 16 + l15;
        float v = acc[i * 4 + j][r];
        if (HAS_BIAS) v += bias[col];
        if (RELU) v = fmaxf(v, 0.f);
        if (RES_MODE == 2) v += (float)resid[(size_t)row * N + col];
        Out[(size_t)row * N + col] = (bf16)v;
        if (STATS) { lsum += v; lsq += v * v; }
      }

  if (STATS) {
    __syncthreads();
    float* red = (float*)As;
    red[tid] = lsum;
    red[256 + tid] = lsq;
    __syncthreads();
    for (int off = 128; off > 0; off >>= 1) {
      if (tid < off) { red[tid] += red[tid + off]; red[256 + tid] += red[256 + tid + off]; }
      __syncthreads();
    }
    if (tid == 0) {
      int bidx = (rowOfs + m0) >> 12;  // 4096 rows per batch
      atomicAdd(&stats[bidx * 2], red[0]);
      atomicAdd(&stats[bidx * 2 + 1], red[256]);
    }
  }
}

// ---------------- LayerNorm apply over (S,D) jointly per batch ----------------
template <bool FINAL>
__global__ void k_ln(const bf16* __restrict__ T, const float* __restrict__ stats,
                     const void* __restrict__ gp, const void* __restrict__ bp,
                     void* __restrict__ outp, const unsigned* __restrict__ flag) {
  const float invN = 1.f / 2097152.f;
  size_t i = ((size_t)(blockIdx.x * 256 + threadIdx.x)) * 8;
  int b = (int)(i >> 21);
  int sd = (int)(i & 2097151);
  float mu = stats[b * 2] * invN;
  float var = stats[b * 2 + 1] * invN - mu * mu;
  float rs = rsqrtf(var + 1e-5f);
  bool f32m = (*flag != 0);
  bf16x8 tv = *(const bf16x8*)(T + i);
  float gv[8], bv[8];
  if (f32m) {
    float4 a = *(const float4*)((const float*)gp + sd), c = *(const float4*)((const float*)gp + sd + 4);
    gv[0] = a.x; gv[1] = a.y; gv[2] = a.z; gv[3] = a.w; gv[4] = c.x; gv[5] = c.y; gv[6] = c.z; gv[7] = c.w;
    float4 e = *(const float4*)((const float*)bp + sd), f = *(const float4*)((const float*)bp + sd + 4);
    bv[0] = e.x; bv[1] = e.y; bv[2] = e.z; bv[3] = e.w; bv[4] = f.x; bv[5] = f.y; bv[6] = f.z; bv[7] = f.w;
  } else {
    bf16x8 g8 = *(const bf16x8*)((const bf16*)gp + sd);
    bf16x8 b8 = *(const bf16x8*)((const bf16*)bp + sd);
#pragma unroll
    for (int k = 0; k < 8; ++k) { gv[k] = (float)g8[k]; bv[k] = (float)b8[k]; }
  }
  float ov[8];
#pragma unroll
  for (int k = 0; k < 8; ++k) ov[k] = ((float)tv[k] - mu) * rs * gv[k] + bv[k];
  if (FINAL && f32m) {
    float4 o0 = {ov[0], ov[1], ov[2], ov[3]}, o1 = {ov[4], ov[5], ov[6], ov[7]};
    *(float4*)((float*)outp + i) = o0;
    *(float4*)((float*)outp + i + 4) = o1;
  } else {
    bf16x8 o8;
#pragma unroll
    for (int k = 0; k < 8; ++k) o8[k] = (bf16)ov[k];
    *(bf16x8*)((bf16*)outp + i) = o8;
  }
}

// ---------------- fused LayerNorm + transpose: X = LN(T), XT = X^T (k-swizzled) ----------------
__global__ void k_ln_t(const bf16* __restrict__ T, const float* __restrict__ stats,
                       const void* __restrict__ gp, const void* __restrict__ bp,
                       bf16* __restrict__ X, bf16* __restrict__ XT,
                       const unsigned* __restrict__ flag) {
  __shared__ bf16 t[64][72];
  const float invN = 1.f / 2097152.f;
  const int b = blockIdx.z, s0 = blockIdx.x * 64, d0 = blockIdx.y * 64;
  const int tid = threadIdx.x;
  const float mu = stats[b * 2] * invN;
  const float var = stats[b * 2 + 1] * invN - mu * mu;
  const float rs = rsqrtf(var + 1e-5f);
  const bool f32m = (*flag != 0);
#pragma unroll
  for (int it = 0; it < 2; ++it) {
    int slot = it * 256 + tid;
    int r = slot >> 3, c = (slot & 7) * 8;
    size_t idx = ((size_t)b * NS + s0 + r) * ND + d0 + c;
    size_t pidx = (size_t)(s0 + r) * ND + d0 + c;
    bf16x8 tv = *(const bf16x8*)&T[idx];
    float gv[8], bv[8];
    if (f32m) {
      float4 a = *(const float4*)((const float*)gp + pidx), cc = *(const float4*)((const float*)gp + pidx + 4);
      gv[0] = a.x; gv[1] = a.y; gv[2] = a.z; gv[3] = a.w; gv[4] = cc.x; gv[5] = cc.y; gv[6] = cc.z; gv[7] = cc.w;
      float4 e = *(const float4*)((const float*)bp + pidx), f = *(const float4*)((const float*)bp + pidx + 4);
      bv[0] = e.x; bv[1] = e.y; bv[2] = e.z; bv[3] = e.w; bv[4] = f.x; bv[5] = f.y; bv[6] = f.z; bv[7] = f.w;
    } else {
      bf16x8 g8 = *(const bf16x8*)((const bf16*)gp + pidx);
      bf16x8 b8 = *(const bf16x8*)((const bf16*)bp + pidx);
#pragma unroll
      for (int k = 0; k < 8; ++k) { gv[k] = (float)g8[k]; bv[k] = (float)b8[k]; }
    }
    bf16x8 ov;
#pragma unroll
    for (int k = 0; k < 8; ++k) ov[k] = (bf16)(((float)tv[k] - mu) * rs * gv[k] + bv[k]);
    *(bf16x8*)&X[idx] = ov;
    *(bf16x8*)&t[r][c] = ov;
  }
  __syncthreads();
#pragma unroll
  for (int it = 0; it < 2; ++it) {
    int slot = it * 256 + tid;
    int r = slot >> 3, c = (slot & 7) * 8;  // r = local dim, c = local seq base
    bf16x8 v;
#pragma unroll
    for (int k = 0; k < 8; ++k) v[k] = t[c + k][r];
    *(bf16x8*)&XT[((size_t)b * ND + d0 + r) * NS + s0 + vswz_col(c, r)] = v;
  }
}

// ---------------- launch ----------------
extern "C" void kernel_launch(void* const* d_in, const int* in_sizes, int n_in, void* d_out,
                              int out_size, void* d_ws, size_t ws_size, hipStream_t stream) {
  (void)in_sizes; (void)n_in; (void)out_size;
  const void* x_raw = d_in[0];
  const void* enc_raw = d_in[1];
  const void* Wo1_raw = d_in[2];
  const void* Wo2_raw = d_in[3];
  const void* g1_raw = d_in[4];
  const void* bb1_raw = d_in[5];
  const void* g2_raw = d_in[6];
  const void* bb2_raw = d_in[7];
  const void* W1_raw = d_in[8];
  const void* bias1_raw = d_in[9];
  const void* W2_raw = d_in[10];
  const void* bias2_raw = d_in[11];

  char* w = (char*)d_ws;
  unsigned* flag = (unsigned*)(w + 0);
  float* stats = (float*)(w + 16);  // 3 stages x [B][2]
  float* b1f = (float*)(w + 1024);
  float* b2f = (float*)(w + 1024 + 8192);
  size_t off = 16384;
  const size_t nBSD = (size_t)NB * NS * ND;
  bf16* Wo1b = (bf16*)(w + off); off += (size_t)ND * ND * 2;
  bf16* Wo2b = (bf16*)(w + off); off += (size_t)ND * ND * 2;
  bf16* W1b = (bf16*)(w + off); off += (size_t)NF * ND * 2;
  bf16* W2b = (bf16*)(w + off); off += (size_t)ND * NF * 2;
  bf16* xb = (bf16*)(w + off); off += nBSD * 2;   // x bf16, later enc
  bf16* Ab = (bf16*)(w + off); off += nBSD * 2;
  bf16* Tb = (bf16*)(w + off); off += nBSD * 2;
  bf16* X1b = (bf16*)(w + off); off += nBSD * 2;
  bf16* Hb = (bf16*)(w + off);  // FFN hidden; attn partial-1 + ml earlier
  const size_t hbFull = (size_t)NB * NS * NF * 2;  // 64 MB (full-M FFN)
  const size_t hbHalf = hbFull / 2;                // 32 MB (2-chunk FFN)
  const bool ffnFull = (ws_size >= off + hbFull);
  if (!ffnFull && ws_size < off + hbHalf) return;

  bf16* O1b = Hb;                                 // partial-1 region (Hb dead until FFN)
  float2* mlb = (float2*)((char*)Hb + nBSD * 2);  // 2*B*S float2 = 256 KB

  hipMemsetAsync(stats, 0, 24 * sizeof(float), stream);
  k_detect<<<1, 256, 0, stream>>>((const unsigned short*)x_raw, flag);

  k_norm_bf16<<<(int)(nBSD / 2048), 256, 0, stream>>>(x_raw, xb, flag, (int)nBSD);
  k_norm_bf16<<<(ND * ND) / 2048, 256, 0, stream>>>(Wo1_raw, Wo1b, flag, ND * ND);
  k_norm_bf16<<<(ND * ND) / 2048, 256, 0, stream>>>(Wo2_raw, Wo2b, flag, ND * ND);
  k_norm_bf16<<<(NF * ND) / 2048, 256, 0, stream>>>(W1_raw, W1b, flag, NF * ND);
  k_norm_bf16<<<(NF * ND) / 2048, 256, 0, stream>>>(W2_raw, W2b, flag, ND * NF);
  k_norm_f32<<<8, 256, 0, stream>>>(bias1_raw, b1f, flag, NF);
  k_norm_f32<<<2, 256, 0, stream>>>(bias2_raw, b2f, flag, ND);

  // 1) causal self-attention + Wo1 + residual(x) + LN1 (fused with transpose for cross-attn V)
  k_transpose<<<dim3(NS / 64, ND / 64, NB), 256, 0, stream>>>(xb, Tb);  // x^T (swizzled) as V
  k_attn6<true><<<512, 256, 0, stream>>>(xb, xb, Tb, Ab, O1b, mlb);
  k_merge<<<(int)(nBSD / 2048), 256, 0, stream>>>(Ab, O1b, mlb);
  k_gemm<2, false, false, true><<<dim3(128, 4), 256, 0, stream>>>(Ab, Wo1b, xb, nullptr, Tb,
                                                                  stats + 0, NB * NS, ND, ND, 0);
  k_ln_t<<<dim3(NS / 64, ND / 64, NB), 256, 0, stream>>>(Tb, stats + 0, g1_raw, bb1_raw, X1b, Ab,
                                                         flag);  // X1 -> X1b, X1^T (swizzled) -> Ab
  k_norm_bf16<<<(int)(nBSD / 2048), 256, 0, stream>>>(enc_raw, xb, flag, (int)nBSD);  // xb := enc

  // 2) cross attention (q=k=enc, v=X1) + Wo2 + residual(X1) + LN2
  k_attn6<false><<<512, 256, 0, stream>>>(xb, xb, Ab, Tb, O1b, mlb);  // O0 -> Tb
  k_merge<<<(int)(nBSD / 2048), 256, 0, stream>>>(Tb, O1b, mlb);
  k_gemm<2, false, false, true><<<dim3(128, 4), 256, 0, stream>>>(Tb, Wo2b, X1b, nullptr, Ab,
                                                                  stats + 8, NB * NS, ND, ND, 0);
  k_ln<false><<<(int)(nBSD / 2048), 256, 0, stream>>>(Ab, stats + 8, g2_raw, bb2_raw, X1b, flag);
  // X1b now holds X2

  // 3) FFN + residual(X2) + LN (ln2 params). Full-M single pass if ws allows (FFN2: 2 blocks/CU).
  const int nChunk = ffnFull ? 1 : 2;
  const int rows = ffnFull ? (NB * NS) : 8192;
  for (int c = 0; c < nChunk; ++c) {
    size_t ro = (size_t)c * rows;
    k_gemm<0, true, true, false><<<dim3(rows / 128, 16), 256, 0, stream>>>(
        X1b + ro * ND, W1b, nullptr, b1f, Hb, nullptr, rows, NF, ND, 0);
    k_gemm<2, true, false, true><<<dim3(rows / 128, 4), 256, 0, stream>>>(
        Hb, W2b, X1b + ro * ND, b2f, Tb + ro * ND, stats + 16, rows, ND, NF, (int)ro);
  }
  k_ln<true><<<(int)(nBSD / 2048), 256, 0, stream>>>(Tb, stats + 16, g2_raw, bb2_raw, d_out, flag);
}